// Round 4
// baseline (580.144 us; speedup 1.0000x reference)
//
#include <hip/hip_runtime.h>

constexpr float kAlpha = 0.1f;
constexpr float kBeta  = 1.1f;
constexpr int   kC     = 16;
constexpr int   kD     = 512;
constexpr float kEps   = 1e-8f;

// ws layout (float offsets)
constexpr int SUMS_OFF = 0;       // kC*kD = 8192 floats
constexpr int CNT_OFF  = 8192;    // 16
constexpr int TOT_OFF  = 8208;    // 1
constexpr int CN_OFF   = 8224;    // 8192 (16B aligned)
constexpr int MSK_OFF  = 16416;   // 16 (unsigned)
constexpr int SCL_OFF  = 16432;   // [0]=denom, [1]=num_pairs
constexpr int ZERO_FLOATS = 8209; // sums + cnt + total

__device__ __forceinline__ float dot4(float4 a, float4 b) {
    return a.x * b.x + a.y * b.y + a.z * b.z + a.w * b.w;
}
__device__ __forceinline__ void add4(float4& a, float4 b) {
    a.x += b.x; a.y += b.y; a.z += b.z; a.w += b.w;
}

// ---------------------------------------------------------------- K1: class sums + counts
// One full row per wave per step. Label is wave-uniform -> scalar switch
// (branch tree, ~1-2 taken branches/row instead of 32). Ping-pong register
// pipeline keeps next row's loads in flight across the accumulate.
__global__ __launch_bounds__(256) void k1_sums(const float* __restrict__ emb,
                                               const int* __restrict__ labels,
                                               float* __restrict__ sums,
                                               float* __restrict__ cnt,
                                               int N, int rpb) {
    __shared__ float lacc[kC * kD];   // 32 KB
    __shared__ float lcnt[kC];
    int tid = threadIdx.x;
    int wave = tid >> 6, lane = tid & 63;

    for (int i = tid; i < kC * kD; i += 256) lacc[i] = 0.f;
    if (tid < kC) lcnt[tid] = 0.f;

    // accA[c]: dims [4*lane, 4*lane+4); accB[c]: dims [256+4*lane, ...)
    float4 accA[kC], accB[kC];
#pragma unroll
    for (int c = 0; c < kC; ++c) {
        accA[c] = make_float4(0.f, 0.f, 0.f, 0.f);
        accB[c] = make_float4(0.f, 0.f, 0.f, 0.f);
    }
    float cacc = 0.f;

    const float4* e4 = (const float4*)emb;  // row stride = 128 float4
    int r0 = blockIdx.x * rpb;
    int r1 = min(r0 + rpb, N);

#define ACC1(c) { add4(accA[c], a0); add4(accB[c], a1); }
#define DO_SWITCH(l)                                                        \
    switch (l) {                                                            \
        case 0:  ACC1(0);  break; case 1:  ACC1(1);  break;                 \
        case 2:  ACC1(2);  break; case 3:  ACC1(3);  break;                 \
        case 4:  ACC1(4);  break; case 5:  ACC1(5);  break;                 \
        case 6:  ACC1(6);  break; case 7:  ACC1(7);  break;                 \
        case 8:  ACC1(8);  break; case 9:  ACC1(9);  break;                 \
        case 10: ACC1(10); break; case 11: ACC1(11); break;                 \
        case 12: ACC1(12); break; case 13: ACC1(13); break;                 \
        case 14: ACC1(14); break; default: ACC1(15); break;                 \
    }

    int r = r0 + wave;
    bool v = (r < r1);
    int rc = v ? r : 0;
    float4 a0 = e4[(size_t)rc * 128 + lane];
    float4 a1 = e4[(size_t)rc * 128 + 64 + lane];
    int la = labels[rc];

    while (v) {
        int rn = r + 4;
        bool vn = (rn < r1);
        int rcn = vn ? rn : 0;
        // prefetch next row before the branchy accumulate
        float4 b0 = e4[(size_t)rcn * 128 + lane];
        float4 b1 = e4[(size_t)rcn * 128 + 64 + lane];
        int lb = labels[rcn];

        int l = __builtin_amdgcn_readfirstlane(la);
        DO_SWITCH(l);
        cacc += (lane < kC && l == lane) ? 1.f : 0.f;

        a0 = b0; a1 = b1; la = lb;
        r = rn; v = vn;
    }
#undef DO_SWITCH
#undef ACC1

    // flush: registers -> LDS (atomic across 4 waves) -> global (atomic)
    __syncthreads();
#pragma unroll
    for (int c = 0; c < kC; ++c) {
        float* pA = &lacc[c * kD + 4 * lane];
        atomicAdd(pA + 0, accA[c].x);
        atomicAdd(pA + 1, accA[c].y);
        atomicAdd(pA + 2, accA[c].z);
        atomicAdd(pA + 3, accA[c].w);
        float* pB = &lacc[c * kD + 256 + 4 * lane];
        atomicAdd(pB + 0, accB[c].x);
        atomicAdd(pB + 1, accB[c].y);
        atomicAdd(pB + 2, accB[c].z);
        atomicAdd(pB + 3, accB[c].w);
    }
    if (lane < kC) atomicAdd(&lcnt[lane], cacc);
    __syncthreads();
    for (int i = tid; i < kC * kD; i += 256) atomicAdd(&sums[i], lacc[i]);
    if (tid < kC) atomicAdd(&cnt[tid], lcnt[tid]);
}

// ---------------------------------------------------------------- K2: centroids, pair logic (1 block)
__global__ __launch_bounds__(256) void k2_cent(const float* __restrict__ sums,
                                               const float* __restrict__ cnt_g,
                                               float* __restrict__ cn_g,
                                               unsigned* __restrict__ mask_g,
                                               float* __restrict__ scal) {
    __shared__ __align__(16) float lcn[kC * kD];  // 32 KB
    __shared__ float lcnt[kC];
    __shared__ float red[256];
    __shared__ float norms[kC];
    __shared__ float pdm[kC * kC];
    int tid = threadIdx.x;
    if (tid < kC) lcnt[tid] = cnt_g[tid];
    __syncthreads();

    int c = tid >> 4, sub = tid & 15;
    float invc = 1.f / fmaxf(lcnt[c], 1.f);
    float sq = 0.f;
    for (int d = sub; d < kD; d += 16) {
        float v = sums[c * kD + d] * invc;
        lcn[c * kD + d] = v;
        sq += v * v;
    }
    red[tid] = sq;
    __syncthreads();
    if (tid < kC) {
        float t = 0.f;
        for (int k = 0; k < 16; ++k) t += red[tid * 16 + k];
        norms[tid] = fmaxf(sqrtf(t), kEps);
    }
    __syncthreads();
    for (int i = tid; i < kC * kD; i += 256) {
        float v = lcn[i] / norms[i / kD];
        lcn[i] = v;
        cn_g[i] = v;
    }
    __syncthreads();
    int pi = tid >> 4, pj = tid & 15;
    float dot = 0.f;
    for (int dd = 0; dd < kD; ++dd) {
        int d = (dd + tid) & (kD - 1);
        dot += lcn[pi * kD + d] * lcn[pj * kD + d];
    }
    pdm[tid] = 1.f - dot;
    __syncthreads();
    if (tid == 0) {
        unsigned m[kC];
        for (int a = 0; a < kC; ++a) m[a] = 0u;
        float npairs = 0.f;
        for (int a = 0; a < kC; ++a)
            for (int b = a + 1; b < kC; ++b) {
                bool close = (pdm[a * kC + b] <= kBeta) && (lcnt[a] > 0.f) && (lcnt[b] > 0.f);
                if (close) { m[a] |= 1u << b; m[b] |= 1u << a; npairs += 1.f; }
            }
        float count = 0.f;
        for (int a = 0; a < kC; ++a) {
            mask_g[a] = m[a];
            count += (float)__popc(m[a]) * lcnt[a];
        }
        scal[0] = fmaxf(count, 1.f);
        scal[1] = npairs;
    }
}

// ---------------------------------------------------------------- K3: main distance pass
// Centroids in REGISTERS (wreg[4][8]: lane = 4-class group g x dim-slice j),
// embeddings tiled through LDS (reg-buffered pipeline), one row per wave,
// 4-level shfl_xor butterfly over j only.
constexpr int TR = 32;   // tile rows; 32*2KB = 64 KB LDS
__global__ __launch_bounds__(512, 2) void k3_main(const float* __restrict__ emb,
                                                  const int* __restrict__ labels,
                                                  const float* __restrict__ cn_g,
                                                  const unsigned* __restrict__ mask_g,
                                                  float* __restrict__ total,
                                                  int N, int rpb) {
    __shared__ __align__(16) float4 xbuf[TR * 128];   // 64 KB
    __shared__ unsigned lmask[kC];
    __shared__ float wsum[8];
    int tid = threadIdx.x;
    int wave = tid >> 6, lane = tid & 63;
    int g = lane >> 4, j = lane & 15;

    const float4* w4 = (const float4*)cn_g;
    float4 wreg[4][8];
#pragma unroll
    for (int c = 0; c < 4; ++c)
#pragma unroll
        for (int i = 0; i < 8; ++i)
            wreg[c][i] = w4[(4 * g + c) * 128 + i * 16 + j];
    if (tid < kC) lmask[tid] = mask_g[tid];

    int r0 = blockIdx.x * rpb;
    int r1 = min(r0 + rpb, N);
    float priv = 0.f;

    const float4* src = (const float4*)emb;
    float4 st[8];

    if (r0 < r1) {
        int avail = (r1 - r0) * 128;
#pragma unroll
        for (int k = 0; k < 8; ++k) {
            int idx = k * 512 + tid;
            st[k] = (idx < avail) ? src[(size_t)r0 * 128 + idx] : make_float4(0.f, 0.f, 0.f, 0.f);
        }
#pragma unroll
        for (int k = 0; k < 8; ++k) xbuf[k * 512 + tid] = st[k];
    }
    __syncthreads();

    for (int rt = r0; rt < r1; rt += TR) {
        int ntile = rt + TR;
        bool more = (ntile < r1);
        if (more) {
            int avail = (r1 - ntile) * 128;
#pragma unroll
            for (int k = 0; k < 8; ++k) {
                int idx = k * 512 + tid;
                st[k] = (idx < avail) ? src[(size_t)ntile * 128 + idx] : make_float4(0.f, 0.f, 0.f, 0.f);
            }
        }

        int rows = min(TR, r1 - rt);
        for (int rr = wave; rr < rows; rr += 8) {
            int row = rt + rr;
            int lab = labels[row];
            const float4* xr = &xbuf[rr * 128];
            float d0 = 0.f, d1 = 0.f, d2 = 0.f, d3 = 0.f, nrm = 0.f;
#pragma unroll
            for (int i = 0; i < 8; ++i) {
                float4 x = xr[i * 16 + j];
                nrm += dot4(x, x);
                d0 += dot4(x, wreg[0][i]);
                d1 += dot4(x, wreg[1][i]);
                d2 += dot4(x, wreg[2][i]);
                d3 += dot4(x, wreg[3][i]);
            }
#pragma unroll
            for (int m = 1; m < 16; m <<= 1) {
                d0 += __shfl_xor(d0, m, 64);
                d1 += __shfl_xor(d1, m, 64);
                d2 += __shfl_xor(d2, m, 64);
                d3 += __shfl_xor(d3, m, 64);
                nrm += __shfl_xor(nrm, m, 64);
            }
            if (j == 0) {
                unsigned mm = lmask[lab];
                float inv = 1.f / fmaxf(sqrtf(nrm), kEps);
                float s = 0.f;
                float dv[4] = {d0, d1, d2, d3};
#pragma unroll
                for (int c = 0; c < 4; ++c) {
                    int cg = 4 * g + c;
                    float dd = 1.f - dv[c] * inv;
                    if ((mm >> cg) & 1u) s += fmaxf(kBeta - dd, 0.f);
                    if (cg == lab) s += (float)__popc(mm) * fmaxf(dd - kAlpha, 0.f);
                }
                priv += s;
            }
        }
        __syncthreads();
        if (more) {
#pragma unroll
            for (int k = 0; k < 8; ++k) xbuf[k * 512 + tid] = st[k];
        }
        __syncthreads();
    }

#pragma unroll
    for (int off = 32; off > 0; off >>= 1) priv += __shfl_down(priv, off, 64);
    if (lane == 0) wsum[wave] = priv;
    __syncthreads();
    if (tid == 0) {
        float t = 0.f;
#pragma unroll
        for (int w = 0; w < 8; ++w) t += wsum[w];
        atomicAdd(total, t);
    }
}

// ---------------------------------------------------------------- K4: epilogue
__global__ void k4_final(const float* __restrict__ total,
                         const float* __restrict__ scal,
                         float* __restrict__ out) {
    out[0] = (scal[1] > 0.f) ? (total[0] / scal[0]) : 0.f;
}

extern "C" void kernel_launch(void* const* d_in, const int* in_sizes, int n_in,
                              void* d_out, int out_size, void* d_ws, size_t ws_size,
                              hipStream_t stream) {
    const float* emb = (const float*)d_in[0];
    const int* labels = (const int*)d_in[1];
    int N = in_sizes[0] / kD;

    float* ws = (float*)d_ws;
    float* sums = ws + SUMS_OFF;
    float* cnt = ws + CNT_OFF;
    float* total = ws + TOT_OFF;
    float* cn = ws + CN_OFF;
    unsigned* mask = (unsigned*)(ws + MSK_OFF);
    float* scal = ws + SCL_OFF;

    hipMemsetAsync(d_ws, 0, ZERO_FLOATS * sizeof(float), stream);

    int blocks1 = 512;
    int rpb1 = (N + blocks1 - 1) / blocks1;
    k1_sums<<<blocks1, 256, 0, stream>>>(emb, labels, sums, cnt, N, rpb1);

    k2_cent<<<1, 256, 0, stream>>>(sums, cnt, cn, mask, scal);

    int blocks3 = 256;
    int rpb3 = (N + blocks3 - 1) / blocks3;
    k3_main<<<blocks3, 512, 0, stream>>>(emb, labels, cn, mask, total, N, rpb3);

    k4_final<<<1, 1, 0, stream>>>(total, scal, (float*)d_out);
}